// Round 5
// baseline (128.084 us; speedup 1.0000x reference)
//
#include <hip/hip_runtime.h>
#include <math.h>

#define BB 4
#define NN 128
#define LK 16384      // n*n
#define DD 64
#define HH 4
#define DHH 16
#define TI2 32        // q-rows per block
#define KROWS 64      // staged k rows per chunk
#define KPAD 72       // floats per LDS row (288B): 2-way bank aliasing (free)
#define QK_SCALE 0.3606737602f   // 0.25 * log2(e): exp(d/4) == exp2(d*QK_SCALE)

__device__ __forceinline__ float fexp2(float x){
#if __has_builtin(__builtin_amdgcn_exp2f)
  return __builtin_amdgcn_exp2f(x);   // v_exp_f32
#else
  return __expf(x * 0.6931471806f);
#endif
}

// ---- mask dtype classification via wave ballots: 0=int32, 1=uint8, 2=float32
__device__ __forceinline__ int compute_mode(const void* __restrict__ qmask){
  const unsigned int* w = (const unsigned int*)qmask;
  const int t = threadIdx.x & 63;
  int u8 = 0, i32 = 0, f32 = 0;
  #pragma unroll
  for (int rep = 0; rep < 2; ++rep){
    const unsigned int x = w[t + rep*64];   // first 512B: in-bounds for every dtype
    const bool one  = (x == 1u);
    const bool fone = (x == 0x3f800000u);
    const bool nz   = (x != 0u);
    u8  += __popcll(__ballot(nz && !one && !fone));
    i32 += __popcll(__ballot(one));
    f32 += __popcll(__ballot(fone));
  }
  int mode = 0;
  if (u8 > i32 && u8 > f32) mode = 1;
  else if (f32 > i32) mode = 2;
  return mode;
}

__device__ __forceinline__ bool mget(const void* __restrict__ p, int idx, int mode){
  if (mode == 1) return ((const unsigned char*)p)[idx] != 0;
  if (mode == 2) return ((const float*)p)[idx] != 0.0f;
  return ((const int*)p)[idx] != 0;
}

__device__ __forceinline__ float dot16(float4 q0, float4 q1, float4 q2, float4 q3,
                                       float4 k0, float4 k1, float4 k2, float4 k3){
  float d;
  d = q0.x*k0.x;         d = fmaf(q0.y,k0.y,d); d = fmaf(q0.z,k0.z,d); d = fmaf(q0.w,k0.w,d);
  d = fmaf(q1.x,k1.x,d); d = fmaf(q1.y,k1.y,d); d = fmaf(q1.z,k1.z,d); d = fmaf(q1.w,k1.w,d);
  d = fmaf(q2.x,k2.x,d); d = fmaf(q2.y,k2.y,d); d = fmaf(q2.z,k2.z,d); d = fmaf(q2.w,k2.w,d);
  d = fmaf(q3.x,k3.x,d); d = fmaf(q3.y,k3.y,d); d = fmaf(q3.z,k3.z,d); d = fmaf(q3.w,k3.w,d);
  return d;
}

// stage KROWS k-records (256B each) into padded LDS, pre-scaled by QK_SCALE;
// fully coalesced global reads (contiguous float4 per lane)
__device__ __forceinline__ void stage_k(const float* __restrict__ kA, int b, int lbase,
                                        float* __restrict__ ldsK){
  const int t = threadIdx.x;
  const float4* src = (const float4*)(kA + ((size_t)(b*LK + lbase))*DD);
  #pragma unroll
  for (int p = 0; p < 4; ++p){
    const int f = p*256 + t;          // float4 index 0..1023 over 16KB
    float4 v = src[f];
    v.x *= QK_SCALE; v.y *= QK_SCALE; v.z *= QK_SCALE; v.w *= QK_SCALE;
    *(float4*)(ldsK + (f >> 4)*KPAD + (f & 15)*4) = v;
  }
}

// ---- pass 1: per-(h,row) sum of exp2 over this block's l-span ----
// wave = head; lane = staged l (k from LDS regs); q via wave-uniform global loads
__global__ __launch_bounds__(256) void k1_rowsum(
    const float* __restrict__ qA, const float* __restrict__ kA,
    const void* __restrict__ qm, const void* __restrict__ km,
    float* __restrict__ partials)
{
  __shared__ float ldsK[KROWS*KPAD];
  __shared__ float ldsP[HH][TI2];
  const int mode = compute_mode(qm);
  const int nl = gridDim.x;
  const int chunks = (LK/nl)/KROWS;
  const int lc = blockIdx.x, it = blockIdx.y, b = blockIdx.z;
  const int t = threadIdx.x, w = t >> 6, ll = t & 63;
  const int hs = __builtin_amdgcn_readfirstlane(w);    // uniform head index
  const int ibase = it*TI2;
  const float* qbase = qA + ((size_t)(b*NN + ibase))*DD + hs*DHH;

  float s[TI2];
  #pragma unroll
  for (int i = 0; i < TI2; ++i) s[i] = 0.0f;

  const int lbase0 = lc*(LK/nl);
  for (int jj = 0; jj < chunks; ++jj){
    if (jj) __syncthreads();
    stage_k(kA, b, lbase0 + jj*KROWS, ldsK);
    __syncthreads();

    const int l  = lbase0 + jj*KROWS + ll;
    const int jn = l >> 7, kn = l & 127;
    const bool kv = (jn != kn) && mget(km, b*LK + l, mode);
    unsigned vmask = kv ? 0xFFFFFFFFu : 0u;
    if ((unsigned)(jn - ibase) < TI2) vmask &= ~(1u << (jn - ibase));
    if ((unsigned)(kn - ibase) < TI2) vmask &= ~(1u << (kn - ibase));

    const float* kp = ldsK + ll*KPAD + hs*DHH;
    const float4 k0 = *(const float4*)(kp),    k1 = *(const float4*)(kp+4),
                 k2 = *(const float4*)(kp+8),  k3 = *(const float4*)(kp+12);

    #pragma unroll
    for (int i = 0; i < TI2; ++i){
      const float4* qp = (const float4*)(qbase + i*DD);  // uniform addr: L1 bcast
      float d = dot16(qp[0], qp[1], qp[2], qp[3], k0, k1, k2, k3);
      d = (vmask & (1u << i)) ? d : -INFINITY;           // exp2(-inf)=0
      s[i] += fexp2(d);
    }
  }

  #pragma unroll
  for (int i = 0; i < TI2; ++i){
    float v = s[i];
    #pragma unroll
    for (int off = 32; off; off >>= 1) v += __shfl_xor(v, off);
    if (ll == 0) ldsP[w][i] = v;
  }
  __syncthreads();
  if (t < HH*TI2){                 // t = h*32 + i
    const int h = t >> 5, i = t & 31;
    const bool qv = mget(qm, b*NN + ibase + i, mode);
    partials[lc*(BB*HH*NN) + (b*HH + h)*NN + ibase + i] = qv ? ldsP[h][i] : 0.0f;
  }
}

// ---- pass 1b: reduce partials over lc -> reciprocal row sums ----
__global__ void k1_finalize(const float* __restrict__ partials, float* __restrict__ R,
                            int nl){
  const int tid = blockIdx.x*256 + threadIdx.x;   // 0..2047 = (b*HH+h)*NN+ig
  float ssum = 0.0f;
  for (int lc = 0; lc < nl; ++lc) ssum += partials[lc*(BB*HH*NN) + tid];
  R[tid] = (ssum > 0.0f) ? 1.0f/ssum : 0.0f;
}

// ---- pass 2: recompute logits, write normalized alpha (256B/wave contiguous) ----
__global__ __launch_bounds__(256) void k2_emit(
    const float* __restrict__ qA, const float* __restrict__ kA,
    const void* __restrict__ qm, const void* __restrict__ km,
    const float* __restrict__ R, float* __restrict__ out)
{
  __shared__ float ldsK[KROWS*KPAD];
  const int mode = compute_mode(qm);
  const int lc = blockIdx.x, it = blockIdx.y, b = blockIdx.z;
  const int t = threadIdx.x, w = t >> 6, ll = t & 63;
  const int hs = __builtin_amdgcn_readfirstlane(w);
  const int ibase = it*TI2;
  const int lbase = lc*KROWS;

  stage_k(kA, b, lbase, ldsK);
  __syncthreads();

  const int l  = lbase + ll;
  const int jn = l >> 7, kn = l & 127;
  const bool kv = (jn != kn) && mget(km, b*LK + l, mode);
  // q-mask omitted on purpose: masked q-rows have R==0 (K1 zeroes them)
  unsigned vmask = kv ? 0xFFFFFFFFu : 0u;
  if ((unsigned)(jn - ibase) < TI2) vmask &= ~(1u << (jn - ibase));
  if ((unsigned)(kn - ibase) < TI2) vmask &= ~(1u << (kn - ibase));

  const float* kp = ldsK + ll*KPAD + hs*DHH;
  const float4 k0 = *(const float4*)(kp),    k1 = *(const float4*)(kp+4),
               k2 = *(const float4*)(kp+8),  k3 = *(const float4*)(kp+12);

  const float* qbase = qA + ((size_t)(b*NN + ibase))*DD + hs*DHH;
  const float* Rbase = R + (b*HH + hs)*NN + ibase;
  float* op = out + (((size_t)((hs*BB + b)*NN + ibase)) << 14) + lbase + ll;

  #pragma unroll 8
  for (int i = 0; i < TI2; ++i){
    const float4* qp = (const float4*)(qbase + i*DD);    // uniform addr: L1 bcast
    float d = dot16(qp[0], qp[1], qp[2], qp[3], k0, k1, k2, k3);
    d = (vmask & (1u << i)) ? d : -INFINITY;
    const float r = Rbase[i];                            // uniform scalar load
    op[((size_t)i) << 14] = fexp2(d) * r;                // 64 lanes -> 256B contig
  }
}

extern "C" void kernel_launch(void* const* d_in, const int* in_sizes, int n_in,
                              void* d_out, int out_size, void* d_ws, size_t ws_size,
                              hipStream_t stream)
{
  const float* qA = (const float*)d_in[0];
  const float* kA = (const float*)d_in[1];
  const void*  qm = d_in[2];
  const void*  km = d_in[3];
  float* out = (float*)d_out;

  // K1 l-split: 128 chunks if workspace allows (1MB partials), else 64 (512KB)
  const size_t need128 = ((size_t)128*BB*HH*NN + BB*HH*NN)*sizeof(float);
  const int nl1 = (ws_size >= need128) ? 128 : 64;

  float* partials = (float*)d_ws;
  float* R        = partials + (size_t)nl1*BB*HH*NN;

  dim3 g1(nl1, NN/TI2, BB);        // 2048 or 1024 blocks
  k1_rowsum<<<g1, 256, 0, stream>>>(qA, kA, qm, km, partials);
  k1_finalize<<<(BB*HH*NN)/256, 256, 0, stream>>>(partials, R, nl1);
  dim3 g2(LK/KROWS, NN/TI2, BB);   // (256, 4, 4) = 4096 blocks
  k2_emit<<<g2, 256, 0, stream>>>(qA, kA, qm, km, R, out);
}

// Round 6
// 121.380 us; speedup vs baseline: 1.0552x; 1.0552x over previous
//
#include <hip/hip_runtime.h>
#include <math.h>

#define BB 4
#define NN 128
#define LK 16384      // n*n
#define DD 64
#define HH 4
#define DHH 16
#define TI1 32        // K1 q-rows per block
#define KROWS 64      // staged k rows per chunk
#define KPAD 72       // floats per LDS row (288B)
#define QK_SCALE 0.3606737602f   // 0.25 * log2(e): exp(d/4) == exp2(d*QK_SCALE)

__device__ __forceinline__ float fexp2(float x){
#if __has_builtin(__builtin_amdgcn_exp2f)
  return __builtin_amdgcn_exp2f(x);   // v_exp_f32
#else
  return __expf(x * 0.6931471806f);
#endif
}

// ---- mask dtype classification via wave ballots: 0=int32, 1=uint8, 2=float32
__device__ __forceinline__ int compute_mode(const void* __restrict__ qmask){
  const unsigned int* w = (const unsigned int*)qmask;
  const int t = threadIdx.x & 63;
  int u8 = 0, i32 = 0, f32 = 0;
  #pragma unroll
  for (int rep = 0; rep < 2; ++rep){
    const unsigned int x = w[t + rep*64];   // first 512B: in-bounds for every dtype
    const bool one  = (x == 1u);
    const bool fone = (x == 0x3f800000u);
    const bool nz   = (x != 0u);
    u8  += __popcll(__ballot(nz && !one && !fone));
    i32 += __popcll(__ballot(one));
    f32 += __popcll(__ballot(fone));
  }
  int mode = 0;
  if (u8 > i32 && u8 > f32) mode = 1;
  else if (f32 > i32) mode = 2;
  return mode;
}

__device__ __forceinline__ bool mget(const void* __restrict__ p, int idx, int mode){
  if (mode == 1) return ((const unsigned char*)p)[idx] != 0;
  if (mode == 2) return ((const float*)p)[idx] != 0.0f;
  return ((const int*)p)[idx] != 0;
}

__device__ __forceinline__ float dot16(float4 q0, float4 q1, float4 q2, float4 q3,
                                       float4 k0, float4 k1, float4 k2, float4 k3){
  float d;
  d = q0.x*k0.x;         d = fmaf(q0.y,k0.y,d); d = fmaf(q0.z,k0.z,d); d = fmaf(q0.w,k0.w,d);
  d = fmaf(q1.x,k1.x,d); d = fmaf(q1.y,k1.y,d); d = fmaf(q1.z,k1.z,d); d = fmaf(q1.w,k1.w,d);
  d = fmaf(q2.x,k2.x,d); d = fmaf(q2.y,k2.y,d); d = fmaf(q2.z,k2.z,d); d = fmaf(q2.w,k2.w,d);
  d = fmaf(q3.x,k3.x,d); d = fmaf(q3.y,k3.y,d); d = fmaf(q3.z,k3.z,d); d = fmaf(q3.w,k3.w,d);
  return d;
}

// stage q rows into LDS, pre-scaled by QK_SCALE (coalesced)
__device__ __forceinline__ void stage_q(const float* __restrict__ qA, int b, int ibase,
                                        int rows, float* __restrict__ ldsQ){
  const int t = threadIdx.x;
  const float4* src = (const float4*)(qA + ((size_t)(b*NN + ibase))*DD);
  for (int f = t; f < rows*(DD/4); f += 256){
    float4 v = src[f];
    v.x *= QK_SCALE; v.y *= QK_SCALE; v.z *= QK_SCALE; v.w *= QK_SCALE;
    *(float4*)(ldsQ + (f >> 4)*DD + (f & 15)*4) = v;
  }
}

// write a prefetched 16KB k-chunk (held in regs) into padded LDS
__device__ __forceinline__ void ldsk_write(const float4 pf[4], float* __restrict__ ldsK){
  const int t = threadIdx.x;
  #pragma unroll
  for (int p = 0; p < 4; ++p){
    const int f = p*256 + t;
    *(float4*)(ldsK + (f >> 4)*KPAD + (f & 15)*4) = pf[p];
  }
}
__device__ __forceinline__ void ldsk_fetch(const float* __restrict__ kA, int b, int lbase,
                                           float4 pf[4]){
  const int t = threadIdx.x;
  const float4* src = (const float4*)(kA + ((size_t)(b*LK + lbase))*DD);
  #pragma unroll
  for (int p = 0; p < 4; ++p) pf[p] = src[p*256 + t];
}

// ---- pass 1: per-(h,row) sum of exp2 over this block's l-span ----
// wave = head; lane = staged l; q from ldsQ broadcast; k prefetched reg->LDS
__global__ __launch_bounds__(256) void k1_rowsum(
    const float* __restrict__ qA, const float* __restrict__ kA,
    const void* __restrict__ qm, const void* __restrict__ km,
    float* __restrict__ partials)
{
  __shared__ float ldsK[KROWS*KPAD];
  __shared__ float ldsQ[TI1*DD];
  __shared__ float ldsP[HH][TI1];
  const int mode = compute_mode(qm);
  const int nl = gridDim.x;
  const int chunks = (LK/nl)/KROWS;
  const int lc = blockIdx.x, it = blockIdx.y, b = blockIdx.z;
  const int t = threadIdx.x, w = t >> 6, ll = t & 63;
  const int hs = __builtin_amdgcn_readfirstlane(w);    // uniform head index
  const int ibase = it*TI1;
  const int lbase0 = lc*(LK/nl);

  stage_q(qA, b, ibase, TI1, ldsQ);

  float s[TI1];
  #pragma unroll
  for (int i = 0; i < TI1; ++i) s[i] = 0.0f;

  float4 pf[4];
  ldsk_fetch(kA, b, lbase0, pf);                // prologue: chunk 0 -> regs

  for (int jj = 0; jj < chunks; ++jj){
    if (jj) __syncthreads();                    // prior chunk's readers done
    ldsk_write(pf, ldsK);
    if (jj + 1 < chunks) ldsk_fetch(kA, b, lbase0 + (jj+1)*KROWS, pf); // overlap
    __syncthreads();

    const int l  = lbase0 + jj*KROWS + ll;
    const int jn = l >> 7, kn = l & 127;
    const bool kv = (jn != kn) && mget(km, b*LK + l, mode);
    unsigned vmask = kv ? 0xFFFFFFFFu : 0u;
    if ((unsigned)(jn - ibase) < TI1) vmask &= ~(1u << (jn - ibase));
    if ((unsigned)(kn - ibase) < TI1) vmask &= ~(1u << (kn - ibase));

    const float* kp = ldsK + ll*KPAD + hs*DHH;
    const float4 k0 = *(const float4*)(kp),    k1 = *(const float4*)(kp+4),
                 k2 = *(const float4*)(kp+8),  k3 = *(const float4*)(kp+12);

    #pragma unroll
    for (int i = 0; i < TI1; ++i){
      const float* qp = ldsQ + i*DD + hs*DHH;    // uniform addr -> LDS broadcast
      float d = dot16(*(const float4*)(qp),   *(const float4*)(qp+4),
                      *(const float4*)(qp+8), *(const float4*)(qp+12),
                      k0, k1, k2, k3);
      d = (vmask & (1u << i)) ? d : -INFINITY;   // exp2(-inf)=0
      s[i] += fexp2(d);
    }
  }

  #pragma unroll
  for (int i = 0; i < TI1; ++i){
    float v = s[i];
    #pragma unroll
    for (int off = 32; off; off >>= 1) v += __shfl_xor(v, off);
    if (ll == 0) ldsP[w][i] = v;
  }
  __syncthreads();
  if (t < HH*TI1){                 // t = h*32 + i
    const int h = t >> 5, i = t & 31;
    const bool qv = mget(qm, b*NN + ibase + i, mode);
    partials[lc*(BB*HH*NN) + (b*HH + h)*NN + ibase + i] = qv ? ldsP[h][i] : 0.0f;
  }
}

// ---- pass 1b: reduce partials over lc -> reciprocal row sums ----
__global__ void k1_finalize(const float* __restrict__ partials, float* __restrict__ R,
                            int nl){
  const int tid = blockIdx.x*256 + threadIdx.x;   // 0..2047 = (b*HH+h)*NN+ig
  float ssum = 0.0f;
  for (int lc = 0; lc < nl; ++lc) ssum += partials[lc*(BB*HH*NN) + tid];
  R[tid] = (ssum > 0.0f) ? 1.0f/ssum : 0.0f;
}

// ---- pass 2: recompute logits, write normalized alpha (256B/wave contiguous) ----
// One block per (l-chunk, b): k staged ONCE, i-loop covers all 128 q-rows.
__global__ __launch_bounds__(256) void k2_emit(
    const float* __restrict__ qA, const float* __restrict__ kA,
    const void* __restrict__ qm, const void* __restrict__ km,
    const float* __restrict__ R, float* __restrict__ out)
{
  __shared__ float ldsK[KROWS*KPAD];   // 18 KB
  __shared__ float ldsQ[NN*DD];        // 32 KB
  __shared__ float ldsR[HH*NN];        // 2 KB
  const int mode = compute_mode(qm);
  const int lc = blockIdx.x, b = blockIdx.y;
  const int t = threadIdx.x, w = t >> 6, ll = t & 63;
  const int hs = __builtin_amdgcn_readfirstlane(w);
  const int lbase = lc*KROWS;

  stage_q(qA, b, 0, NN, ldsQ);
  {
    float4 pf[4];
    ldsk_fetch(kA, b, lbase, pf);
    ldsk_write(pf, ldsK);
  }
  for (int f = t; f < HH*NN; f += 256) ldsR[f] = R[b*HH*NN + f];
  __syncthreads();

  const int l  = lbase + ll;
  const int jn = l >> 7, kn = l & 127;
  const bool kv = (jn != kn) && mget(km, b*LK + l, mode);
  // q-mask omitted on purpose: masked q-rows have R==0 (K1 zeroes them)
  unsigned long long m0 = kv ? ~0ull : 0ull, m1 = m0;
  if (jn < 64) m0 &= ~(1ull << jn); else m1 &= ~(1ull << (jn - 64));
  if (kn < 64) m0 &= ~(1ull << kn); else m1 &= ~(1ull << (kn - 64));

  const float* kp = ldsK + ll*KPAD + hs*DHH;
  const float4 k0 = *(const float4*)(kp),    k1 = *(const float4*)(kp+4),
               k2 = *(const float4*)(kp+8),  k3 = *(const float4*)(kp+12);

  const float* Rh = ldsR + hs*NN;
  float* op = out + (((size_t)((hs*BB + b)*NN)) << 14) + lbase + ll;

  #pragma unroll 8
  for (int i = 0; i < NN; ++i){
    const float* qp = ldsQ + i*DD + hs*DHH;    // uniform addr -> LDS broadcast
    float d = dot16(*(const float4*)(qp),   *(const float4*)(qp+4),
                    *(const float4*)(qp+8), *(const float4*)(qp+12),
                    k0, k1, k2, k3);
    const unsigned long long mm = (i & 64) ? m1 : m0;
    d = ((mm >> (i & 63)) & 1ull) ? d : -INFINITY;
    op[((size_t)i) << 14] = fexp2(d) * Rh[i];  // 64 lanes -> 256B contiguous
  }
}

extern "C" void kernel_launch(void* const* d_in, const int* in_sizes, int n_in,
                              void* d_out, int out_size, void* d_ws, size_t ws_size,
                              hipStream_t stream)
{
  const float* qA = (const float*)d_in[0];
  const float* kA = (const float*)d_in[1];
  const void*  qm = d_in[2];
  const void*  km = d_in[3];
  float* out = (float*)d_out;

  // K1 l-split: 128 chunks if workspace allows (1MB partials), else 64 (512KB)
  const size_t need128 = ((size_t)128*BB*HH*NN + BB*HH*NN)*sizeof(float);
  const int nl1 = (ws_size >= need128) ? 128 : 64;

  float* partials = (float*)d_ws;
  float* R        = partials + (size_t)nl1*BB*HH*NN;

  dim3 g1(nl1, NN/TI1, BB);        // 2048 or 1024 blocks
  k1_rowsum<<<g1, 256, 0, stream>>>(qA, kA, qm, km, partials);
  k1_finalize<<<(BB*HH*NN)/256, 256, 0, stream>>>(partials, R, nl1);
  dim3 g2(LK/KROWS, BB);           // (256, 4) = 1024 blocks
  k2_emit<<<g2, 256, 0, stream>>>(qA, kA, qm, km, R, out);
}

// Round 7
// 105.789 us; speedup vs baseline: 1.2107x; 1.1474x over previous
//
#include <hip/hip_runtime.h>
#include <math.h>

#define BB 4
#define NN 128
#define LK 16384      // n*n
#define DD 64
#define HH 4
#define DHH 16
#define TI1 32        // q-rows per block (both passes)
#define KROWS 128     // staged k rows per chunk (each lane owns rows ll and ll+64)
#define KPAD 68       // floats per LDS row (272B): stride%32==4 -> 2-way aliasing (free)
#define QK_SCALE 0.3606737602f   // 0.25 * log2(e): exp(d/4) == exp2(d*QK_SCALE)

__device__ __forceinline__ float fexp2(float x){
#if __has_builtin(__builtin_amdgcn_exp2f)
  return __builtin_amdgcn_exp2f(x);   // v_exp_f32
#else
  return __expf(x * 0.6931471806f);
#endif
}

// ---- mask dtype classification via wave ballots: 0=int32, 1=uint8, 2=float32
__device__ __forceinline__ int compute_mode(const void* __restrict__ qmask){
  const unsigned int* w = (const unsigned int*)qmask;
  const int t = threadIdx.x & 63;
  int u8 = 0, i32 = 0, f32 = 0;
  #pragma unroll
  for (int rep = 0; rep < 2; ++rep){
    const unsigned int x = w[t + rep*64];   // first 512B: in-bounds for every dtype
    const bool one  = (x == 1u);
    const bool fone = (x == 0x3f800000u);
    const bool nz   = (x != 0u);
    u8  += __popcll(__ballot(nz && !one && !fone));
    i32 += __popcll(__ballot(one));
    f32 += __popcll(__ballot(fone));
  }
  int mode = 0;
  if (u8 > i32 && u8 > f32) mode = 1;
  else if (f32 > i32) mode = 2;
  return mode;
}

__device__ __forceinline__ bool mget(const void* __restrict__ p, int idx, int mode){
  if (mode == 1) return ((const unsigned char*)p)[idx] != 0;
  if (mode == 2) return ((const float*)p)[idx] != 0.0f;
  return ((const int*)p)[idx] != 0;
}

__device__ __forceinline__ float dot16(float4 q0, float4 q1, float4 q2, float4 q3,
                                       float4 k0, float4 k1, float4 k2, float4 k3){
  float d;
  d = q0.x*k0.x;         d = fmaf(q0.y,k0.y,d); d = fmaf(q0.z,k0.z,d); d = fmaf(q0.w,k0.w,d);
  d = fmaf(q1.x,k1.x,d); d = fmaf(q1.y,k1.y,d); d = fmaf(q1.z,k1.z,d); d = fmaf(q1.w,k1.w,d);
  d = fmaf(q2.x,k2.x,d); d = fmaf(q2.y,k2.y,d); d = fmaf(q2.z,k2.z,d); d = fmaf(q2.w,k2.w,d);
  d = fmaf(q3.x,k3.x,d); d = fmaf(q3.y,k3.y,d); d = fmaf(q3.z,k3.z,d); d = fmaf(q3.w,k3.w,d);
  return d;
}

// stage KROWS k-records (256B each) into padded LDS; fully coalesced global reads
__device__ __forceinline__ void stage_k(const float* __restrict__ kA, int b, int lbase,
                                        float* __restrict__ ldsK){
  const int t = threadIdx.x;
  const float4* src = (const float4*)(kA + ((size_t)(b*LK + lbase))*DD);
  #pragma unroll
  for (int p = 0; p < KROWS/16; ++p){       // 8 float4 per thread (2 rows' worth)
    const int f = p*256 + t;                // float4 index 0..2047 over 32KB
    const float4 v = src[f];
    *(float4*)(ldsK + (f >> 4)*KPAD + (f & 15)*4) = v;
  }
}

// stage q rows into LDS, pre-scaled by QK_SCALE (coalesced)
__device__ __forceinline__ void stage_q(const float* __restrict__ qA, int b, int ibase,
                                        float* __restrict__ ldsQ){
  const int t = threadIdx.x;
  const float4* src = (const float4*)(qA + ((size_t)(b*NN + ibase))*DD);
  #pragma unroll
  for (int p = 0; p < TI1/16; ++p){
    const int f = p*256 + t;                // 0..511 over 8KB
    float4 v = src[f];
    v.x *= QK_SCALE; v.y *= QK_SCALE; v.z *= QK_SCALE; v.w *= QK_SCALE;
    *(float4*)(ldsQ + (f >> 4)*DD + (f & 15)*4) = v;
  }
}

// per-l validity mask over the block's TI1 q-rows
__device__ __forceinline__ unsigned lane_vmask(const void* __restrict__ km, int b, int l,
                                               int ibase, int mode){
  const int jn = l >> 7, kn = l & 127;
  const bool kv = (jn != kn) && mget(km, b*LK + l, mode);
  unsigned m = kv ? 0xFFFFFFFFu : 0u;
  if ((unsigned)(jn - ibase) < TI1) m &= ~(1u << (jn - ibase));
  if ((unsigned)(kn - ibase) < TI1) m &= ~(1u << (kn - ibase));
  return m;
}

// ---- pass 1: per-(h,row) sum of exp2 over this block's l-span ----
// wave = head; lane owns l = base+ll and base+ll+64; q from ldsQ broadcast
__global__ __launch_bounds__(256) void k1_rowsum(
    const float* __restrict__ qA, const float* __restrict__ kA,
    const void* __restrict__ qm, const void* __restrict__ km,
    float* __restrict__ partials)
{
  __shared__ float ldsK[KROWS*KPAD];     // 34.8 KB
  __shared__ float ldsQ[TI1*DD];         // 8 KB
  __shared__ float ldsP[HH][TI1];
  const int mode = compute_mode(qm);
  const int nl = gridDim.x;
  const int chunks = (LK/nl)/KROWS;
  const int lc = blockIdx.x, it = blockIdx.y, b = blockIdx.z;
  const int t = threadIdx.x, w = t >> 6, ll = t & 63;
  const int hs = __builtin_amdgcn_readfirstlane(w);    // uniform head index
  const int ibase = it*TI1;
  const int lbase0 = lc*(LK/nl);

  stage_q(qA, b, ibase, ldsQ);

  float s[TI1];
  #pragma unroll
  for (int i = 0; i < TI1; ++i) s[i] = 0.0f;

  for (int jj = 0; jj < chunks; ++jj){
    if (jj) __syncthreads();
    stage_k(kA, b, lbase0 + jj*KROWS, ldsK);
    __syncthreads();

    const int la = lbase0 + jj*KROWS + ll;
    const unsigned vma = lane_vmask(km, b, la,      ibase, mode);
    const unsigned vmb = lane_vmask(km, b, la + 64, ibase, mode);

    const float* kpa = ldsK + ll*KPAD + hs*DHH;
    const float* kpb = kpa + 64*KPAD;
    const float4 a0 = *(const float4*)(kpa),    a1 = *(const float4*)(kpa+4),
                 a2 = *(const float4*)(kpa+8),  a3 = *(const float4*)(kpa+12);
    const float4 b0 = *(const float4*)(kpb),    b1 = *(const float4*)(kpb+4),
                 b2 = *(const float4*)(kpb+8),  b3 = *(const float4*)(kpb+12);

    #pragma unroll
    for (int i = 0; i < TI1; ++i){
      const float* qp = ldsQ + i*DD + hs*DHH;    // uniform addr -> LDS broadcast
      const float4 q0 = *(const float4*)(qp),   q1 = *(const float4*)(qp+4),
                   q2 = *(const float4*)(qp+8), q3 = *(const float4*)(qp+12);
      float da = dot16(q0,q1,q2,q3, a0,a1,a2,a3);
      float db = dot16(q0,q1,q2,q3, b0,b1,b2,b3);
      da = (vma & (1u << i)) ? da : -INFINITY;   // exp2(-inf)=0
      db = (vmb & (1u << i)) ? db : -INFINITY;
      s[i] += fexp2(da) + fexp2(db);
    }
  }

  #pragma unroll
  for (int i = 0; i < TI1; ++i){
    float v = s[i];
    #pragma unroll
    for (int off = 32; off; off >>= 1) v += __shfl_xor(v, off);
    if (ll == 0) ldsP[w][i] = v;
  }
  __syncthreads();
  if (t < HH*TI1){                 // t = h*32 + i
    const int h = t >> 5, i = t & 31;
    const bool qv = mget(qm, b*NN + ibase + i, mode);
    partials[lc*(BB*HH*NN) + (b*HH + h)*NN + ibase + i] = qv ? ldsP[h][i] : 0.0f;
  }
}

// ---- pass 1b: reduce partials over lc -> reciprocal row sums ----
__global__ void k1_finalize(const float* __restrict__ partials, float* __restrict__ R,
                            int nl){
  const int tid = blockIdx.x*256 + threadIdx.x;   // 0..2047 = (b*HH+h)*NN+ig
  float ssum = 0.0f;
  for (int lc = 0; lc < nl; ++lc) ssum += partials[lc*(BB*HH*NN) + tid];
  R[tid] = (ssum > 0.0f) ? 1.0f/ssum : 0.0f;
}

// ---- pass 2: recompute logits, write normalized alpha ----
// Lane owns two l (ll, ll+64): two 256B-contiguous wave stores per i-iter;
// 4 q LDS-reads per iter serve 128 elements.
__global__ __launch_bounds__(256) void k2_emit(
    const float* __restrict__ qA, const float* __restrict__ kA,
    const void* __restrict__ qm, const void* __restrict__ km,
    const float* __restrict__ R, float* __restrict__ out)
{
  __shared__ float ldsK[KROWS*KPAD];     // 34.8 KB
  __shared__ float ldsQ[TI1*DD];         // 8 KB
  const int mode = compute_mode(qm);
  const int lc = blockIdx.x, it = blockIdx.y, b = blockIdx.z;
  const int t = threadIdx.x, w = t >> 6, ll = t & 63;
  const int hs = __builtin_amdgcn_readfirstlane(w);
  const int ibase = it*TI1;
  const int lbase = lc*KROWS;

  stage_q(qA, b, ibase, ldsQ);
  stage_k(kA, b, lbase, ldsK);
  __syncthreads();

  const int la = lbase + ll;
  // q-mask omitted on purpose: masked q-rows have R==0 (K1 zeroes them)
  const unsigned vma = lane_vmask(km, b, la,      ibase, mode);
  const unsigned vmb = lane_vmask(km, b, la + 64, ibase, mode);

  const float* kpa = ldsK + ll*KPAD + hs*DHH;
  const float* kpb = kpa + 64*KPAD;
  const float4 a0 = *(const float4*)(kpa),    a1 = *(const float4*)(kpa+4),
               a2 = *(const float4*)(kpa+8),  a3 = *(const float4*)(kpa+12);
  const float4 b0 = *(const float4*)(kpb),    b1 = *(const float4*)(kpb+4),
               b2 = *(const float4*)(kpb+8),  b3 = *(const float4*)(kpb+12);

  const float* Rbase = R + (b*HH + hs)*NN + ibase;
  float* opA = out + (((size_t)((hs*BB + b)*NN + ibase)) << 14) + lbase + ll;
  float* opB = opA + 64;

  #pragma unroll 4
  for (int i = 0; i < TI1; ++i){
    const float* qp = ldsQ + i*DD + hs*DHH;      // uniform addr -> LDS broadcast
    const float4 q0 = *(const float4*)(qp),   q1 = *(const float4*)(qp+4),
                 q2 = *(const float4*)(qp+8), q3 = *(const float4*)(qp+12);
    float da = dot16(q0,q1,q2,q3, a0,a1,a2,a3);
    float db = dot16(q0,q1,q2,q3, b0,b1,b2,b3);
    da = (vma & (1u << i)) ? da : -INFINITY;
    db = (vmb & (1u << i)) ? db : -INFINITY;
    const float r = Rbase[i];                    // uniform scalar load
    opA[((size_t)i) << 14] = fexp2(da) * r;      // 64 lanes -> 256B contiguous
    opB[((size_t)i) << 14] = fexp2(db) * r;
  }
}

extern "C" void kernel_launch(void* const* d_in, const int* in_sizes, int n_in,
                              void* d_out, int out_size, void* d_ws, size_t ws_size,
                              hipStream_t stream)
{
  const float* qA = (const float*)d_in[0];
  const float* kA = (const float*)d_in[1];
  const void*  qm = d_in[2];
  const void*  km = d_in[3];
  float* out = (float*)d_out;

  // K1 l-split: 128 chunks if workspace allows (1MB partials), else 64
  const size_t need128 = ((size_t)128*BB*HH*NN + BB*HH*NN)*sizeof(float);
  const int nl1 = (ws_size >= need128) ? 128 : 64;

  float* partials = (float*)d_ws;
  float* R        = partials + (size_t)nl1*BB*HH*NN;

  dim3 g1(nl1, NN/TI1, BB);          // 2048 (or 1024) blocks
  k1_rowsum<<<g1, 256, 0, stream>>>(qA, kA, qm, km, partials);
  k1_finalize<<<(BB*HH*NN)/256, 256, 0, stream>>>(partials, R, nl1);
  dim3 g2(LK/KROWS, NN/TI1, BB);     // (128, 4, 4) = 2048 blocks
  k2_emit<<<g2, 256, 0, stream>>>(qA, kA, qm, km, R, out);
}